// Round 4
// baseline (1788.308 us; speedup 1.0000x reference)
//
#include <hip/hip_runtime.h>
#include <hip/hip_bf16.h>

typedef __hip_bfloat16 bf16;
typedef unsigned short u16;

#define BATCH 512
#define CW_DIM 4096
#define DIM_CODES 64
#define BOOK_SIZE 1024
#define DIM_EMBED 64
#define ENC_H 512

// ---------------- dtype helpers (bf=1 -> bf16 inputs, bf=0 -> fp32) ----------------
__device__ __forceinline__ float bf2f(u16 u) {
    unsigned int x = ((unsigned int)u) << 16;
    return __uint_as_float(x);
}
__device__ __forceinline__ float loadf(const void* p, size_t i, int bf) {
    if (bf) return bf2f(((const u16*)p)[i]);
    return ((const float*)p)[i];
}
// vector load of 4 consecutive elements (i must be a multiple of 4)
__device__ __forceinline__ float4 load4(const void* p, size_t i, int bf) {
    if (bf) {
        const u16* q = (const u16*)p + i;
        uint2 raw = *reinterpret_cast<const uint2*>(q);
        float4 r;
        r.x = bf2f((u16)(raw.x & 0xFFFF));
        r.y = bf2f((u16)(raw.x >> 16));
        r.z = bf2f((u16)(raw.y & 0xFFFF));
        r.w = bf2f((u16)(raw.y >> 16));
        return r;
    }
    return *reinterpret_cast<const float4*>((const float*)p + i);
}
__device__ __forceinline__ void stored(void* p, size_t i, int bf, double v) {
    if (bf) ((bf16*)p)[i] = __float2bfloat16((float)v);
    else    ((float*)p)[i] = (float)v;
}
__device__ __forceinline__ u16 f2bfu(float v) {
    bf16 b = __float2bfloat16(v);
    return *reinterpret_cast<u16*>(&b);
}

// ---------------- dtype detector ----------------
__global__ void detect_kernel(const u16* __restrict__ x, int* __restrict__ flag) {
    __shared__ int hits;
    if (threadIdx.x == 0) hits = 0;
    __syncthreads();
    int h = 0;
    for (int i = threadIdx.x; i < 16384; i += 256) {
        u16 v = x[2 * i];
        if (((v >> 7) & 0xFF) == 0xFF) h++;
    }
    atomicAdd(&hits, h);
    __syncthreads();
    if (threadIdx.x == 0) *flag = (hits == 0) ? 1 : 0;  // 1 = bf16, 0 = fp32
}

// ---------------- codebook row norms (fp64, vectorized loads) ----------------
__global__ void booknorm_kernel(const void* __restrict__ book, double* __restrict__ bn,
                                const int* __restrict__ dflag) {
    const int bf = *dflag;
    int r = blockIdx.x * blockDim.x + threadIdx.x;
    if (r >= DIM_CODES * BOOK_SIZE) return;
    double acc = 0.0;
    for (int e = 0; e < DIM_EMBED; e += 4) {
        float4 v = load4(book, (size_t)r * DIM_EMBED + e, bf);
        acc = fma((double)v.x, (double)v.x, acc);
        acc = fma((double)v.y, (double)v.y, acc);
        acc = fma((double)v.z, (double)v.z, acc);
        acc = fma((double)v.w, (double)v.w, acc);
    }
    bn[r] = acc;
}

// ---------------- encoder conv + maxpool: 64c x 64h register-tiled mini-GEMM ----------------
__global__ __launch_bounds__(256) void enc_kernel(const void* __restrict__ x,
                                                  const void* __restrict__ w1,
                                                  const void* __restrict__ b1,
                                                  float* __restrict__ hmax,
                                                  const int* __restrict__ dflag) {
    const int bf = *dflag;
    __shared__ float xs_t[64][68];   // [e][c]
    __shared__ float wsh_t[64][68];  // [e][h]
    __shared__ float red[64][17];
    int t = threadIdx.x;
    int h0 = blockIdx.x * 64;
    int b = blockIdx.y;

    int cr = t >> 2;             // 0..63 (c row for x, h row for w1)
    int e0 = (t & 3) << 4;       // 0,16,32,48
    for (int q = 0; q < 4; q++) {
        int e = e0 + (q << 2);
        float4 xv = load4(x, (size_t)b * CW_DIM + cr * DIM_EMBED + e, bf);
        xs_t[e + 0][cr] = xv.x; xs_t[e + 1][cr] = xv.y;
        xs_t[e + 2][cr] = xv.z; xs_t[e + 3][cr] = xv.w;
        float4 wv = load4(w1, (size_t)(h0 + cr) * DIM_EMBED + e, bf);
        wsh_t[e + 0][cr] = wv.x; wsh_t[e + 1][cr] = wv.y;
        wsh_t[e + 2][cr] = wv.z; wsh_t[e + 3][cr] = wv.w;
    }
    __syncthreads();

    int th = t & 15, tc = t >> 4;   // thread tile: 4 c x 4 h
    float acc[4][4] = {};
    for (int e = 0; e < 64; e++) {
        float4 a4 = *(const float4*)&xs_t[e][tc << 2];
        float4 w4 = *(const float4*)&wsh_t[e][th << 2];
        float aa[4] = {a4.x, a4.y, a4.z, a4.w};
        float ww[4] = {w4.x, w4.y, w4.z, w4.w};
#pragma unroll
        for (int i = 0; i < 4; i++)
#pragma unroll
            for (int j = 0; j < 4; j++)
                acc[i][j] = fmaf(aa[i], ww[j], acc[i][j]);
    }
#pragma unroll
    for (int j = 0; j < 4; j++) {
        float bj = loadf(b1, h0 + (th << 2) + j, bf);
        float m = -1e30f;
#pragma unroll
        for (int i = 0; i < 4; i++) {
            float v = acc[i][j] + bj;
            v = v > 0.f ? v : 0.2f * v;
            m = fmaxf(m, v);
        }
        red[(th << 2) + j][tc] = m;
    }
    __syncthreads();
    if (t < 64) {
        float m = red[t][0];
        for (int k = 1; k < 16; k++) m = fmaxf(m, red[t][k]);
        hmax[(size_t)b * ENC_H + h0 + t] = m;
    }
}

// ---------------- fp32 GEMM: C[M,N] = act(A @ W^T + bias), 128x64 tile, 8x4/thread ----------------
// A logically [M,Ktot]: cols [0,K1) from A1 (stride lda1), rest from A2 (stride lda2).
// Aadd (optional, stride lda1): added elementwise to the A1 region (z2 = dfull+pfull fusion).
// Fused epilogue slice-stores: slice s writes C cols [c0,c1) to out[base + m*ostride + (n-c0)]
// in output dtype. Slice boundaries are multiples of 64 -> never straddle a thread's float4.
// Accumulation order (kt asc, kk asc) identical to previous version -> bit-identical results.
__global__ __launch_bounds__(256) void gemm_kernel(const float* __restrict__ A1, int lda1, int K1,
                                                   const float* __restrict__ A2, int lda2, int Ktot,
                                                   const float* __restrict__ Aadd,
                                                   const void* __restrict__ W,
                                                   const void* __restrict__ bias,
                                                   float* __restrict__ C, int N, int act,
                                                   void* __restrict__ out,
                                                   size_t s0base, int s0c0, int s0c1, int s0stride,
                                                   size_t s1base, int s1c0, int s1c1, int s1stride,
                                                   const int* __restrict__ dflag) {
    const int bf = *dflag;
    __shared__ float As[16][136];   // [k][m], pad 136 (mod 32 = 8)
    __shared__ float Ws[16][72];    // [k][n], pad 72  (mod 32 = 8)
    int t = threadIdx.x;
    int tx = t & 15, ty = t >> 4;             // thread tile: rows ty*8..+8, cols tx*4..+4
    int n0 = blockIdx.x * 64, m0 = blockIdx.y * 128;
    int arow = t & 127, ak = (t >> 7) * 8;    // A staging: 8 floats (2 float4), 2-way LDS writes
    int wrow = t & 63,  wk = (t >> 6) * 4;    // W staging: per-wave contiguous rows, 2-way writes
    float acc[8][4] = {};
#pragma unroll 1
    for (int kt = 0; kt < Ktot; kt += 16) {
#pragma unroll
        for (int q = 0; q < 2; q++) {
            int k = kt + ak + q * 4;
            float4 av;
            if (k < K1) {
                av = *reinterpret_cast<const float4*>(A1 + (size_t)(m0 + arow) * lda1 + k);
                if (Aadd) {
                    float4 ad = *reinterpret_cast<const float4*>(Aadd + (size_t)(m0 + arow) * lda1 + k);
                    av.x += ad.x; av.y += ad.y; av.z += ad.z; av.w += ad.w;
                }
            } else {
                av = *reinterpret_cast<const float4*>(A2 + (size_t)(m0 + arow) * lda2 + (k - K1));
            }
            As[ak + q * 4 + 0][arow] = av.x; As[ak + q * 4 + 1][arow] = av.y;
            As[ak + q * 4 + 2][arow] = av.z; As[ak + q * 4 + 3][arow] = av.w;
        }
        float4 wv = load4(W, (size_t)(n0 + wrow) * Ktot + kt + wk, bf);
        Ws[wk + 0][wrow] = wv.x; Ws[wk + 1][wrow] = wv.y;
        Ws[wk + 2][wrow] = wv.z; Ws[wk + 3][wrow] = wv.w;
        __syncthreads();
#pragma unroll
        for (int kk = 0; kk < 16; kk++) {
            float4 a0 = *(const float4*)&As[kk][ty * 8];
            float4 a1 = *(const float4*)&As[kk][ty * 8 + 4];
            float4 w4 = *(const float4*)&Ws[kk][tx * 4];
            float a[8] = {a0.x, a0.y, a0.z, a0.w, a1.x, a1.y, a1.z, a1.w};
            float w[4] = {w4.x, w4.y, w4.z, w4.w};
#pragma unroll
            for (int i = 0; i < 8; i++)
#pragma unroll
                for (int j = 0; j < 4; j++)
                    acc[i][j] = fmaf(a[i], w[j], acc[i][j]);
        }
        __syncthreads();
    }
    int nbase = n0 + tx * 4;
    float b0 = loadf(bias, nbase + 0, bf), b1v = loadf(bias, nbase + 1, bf);
    float b2 = loadf(bias, nbase + 2, bf), b3 = loadf(bias, nbase + 3, bf);
#pragma unroll
    for (int i = 0; i < 8; i++) {
        int m = m0 + ty * 8 + i;
        float ov[4];
        ov[0] = acc[i][0] + b0; ov[1] = acc[i][1] + b1v;
        ov[2] = acc[i][2] + b2; ov[3] = acc[i][3] + b3;
        if (act) {
#pragma unroll
            for (int j = 0; j < 4; j++) ov[j] = ov[j] > 0.f ? ov[j] : 0.2f * ov[j];
        }
        float4 o = {ov[0], ov[1], ov[2], ov[3]};
        *reinterpret_cast<float4*>(C + (size_t)m * N + nbase) = o;
        if (nbase >= s0c0 && nbase < s0c1) {
            size_t off = s0base + (size_t)m * s0stride + (nbase - s0c0);
            if (bf) {
                ushort4 h = {f2bfu(ov[0]), f2bfu(ov[1]), f2bfu(ov[2]), f2bfu(ov[3])};
                *reinterpret_cast<ushort4*>((u16*)out + off) = h;
            } else {
                *reinterpret_cast<float4*>((float*)out + off) = o;
            }
        }
        if (nbase >= s1c0 && nbase < s1c1) {
            size_t off = s1base + (size_t)m * s1stride + (nbase - s1c0);
            if (bf) {
                ushort4 h = {f2bfu(ov[0]), f2bfu(ov[1]), f2bfu(ov[2]), f2bfu(ov[3])};
                *reinterpret_cast<ushort4*>((u16*)out + off) = h;
            } else {
                *reinterpret_cast<float4*>((float*)out + off) = o;
            }
        }
    }
}

// ---------------- fused cw_dist (fp64) + exact argmin ----------------
// grid (c=64, btile=16); block 256 = 4 waves; block covers 32 b-rows x 1024 s.
// Per thread: 8 b-rows as 2 groups of 4 scalar fp64 accumulators.
// #pragma unroll 1 on st-loop: prevents full-unroll + cross-barrier pipelining (spill hazard).
__global__ __launch_bounds__(256, 4) void dist_kernel(const float* __restrict__ cwr,
                                                      const void* __restrict__ book,
                                                      const double* __restrict__ bn,
                                                      void* __restrict__ out,
                                                      size_t odist, size_t oidx,
                                                      const int* __restrict__ dflag) {
    const int bf = *dflag;
    __shared__ double xs[32][64];   // 16 KB
    __shared__ double xn[32];
    __shared__ float bs[64][66];    // float2-aligned; ~2-way eff. bank aliasing (free)
    int t = threadIdx.x;
    int c = blockIdx.x;
    int b0 = blockIdx.y * 32;
    int sl = t & 63, wv = t >> 6;

    for (int i = t; i < 32 * 64; i += 256) {
        int bl = i >> 6, e = i & 63;
        xs[bl][e] = (double)cwr[(size_t)(b0 + bl) * CW_DIM + c * DIM_EMBED + e];
    }
    __syncthreads();
    if (t < 32) {
        double a = 0.0;
        for (int e = 0; e < 64; e++) a = fma(xs[t][e], xs[t][e], a);
        xn[t] = a;
    }

    double bd[8];
    int bsx[8];
#pragma unroll
    for (int p = 0; p < 8; p++) { bd[p] = 1e300; bsx[p] = 0; }

#pragma unroll 1
    for (int st = 0; st < 16; st++) {
        int s0 = st * 64;
        __syncthreads();  // previous-tile readers done (and xn visible on st==0)
#pragma unroll
        for (int i4 = t; i4 < 1024; i4 += 256) {
            int srow = i4 >> 4, e4 = (i4 & 15) << 2;
            float4 v = load4(book, ((size_t)c * BOOK_SIZE + s0 + srow) * DIM_EMBED + e4, bf);
            bs[srow][e4 + 0] = v.x; bs[srow][e4 + 1] = v.y;
            bs[srow][e4 + 2] = v.z; bs[srow][e4 + 3] = v.w;
        }
        __syncthreads();
        double bnv = bn[(size_t)c * BOOK_SIZE + s0 + sl];
#pragma unroll
        for (int pb = 0; pb < 2; pb++) {   // fully unrolled (2): bd/bsx indices compile-time
            int blb = wv * 8 + pb * 4;
            double a0 = 0.0, a1 = 0.0, a2 = 0.0, a3 = 0.0;
#pragma unroll 8
            for (int e = 0; e < 64; e += 2) {
                float2 bv = *(const float2*)&bs[sl][e];
                double bv0 = (double)bv.x, bv1 = (double)bv.y;
                double2 x0 = *(const double2*)&xs[blb + 0][e];
                double2 x1 = *(const double2*)&xs[blb + 1][e];
                double2 x2 = *(const double2*)&xs[blb + 2][e];
                double2 x3 = *(const double2*)&xs[blb + 3][e];
                a0 = fma(x0.x, bv0, a0); a0 = fma(x0.y, bv1, a0);
                a1 = fma(x1.x, bv0, a1); a1 = fma(x1.y, bv1, a1);
                a2 = fma(x2.x, bv0, a2); a2 = fma(x2.y, bv1, a2);
                a3 = fma(x3.x, bv0, a3); a3 = fma(x3.y, bv1, a3);
            }
            double dv[4];
            dv[0] = a0; dv[1] = a1; dv[2] = a2; dv[3] = a3;
#pragma unroll
            for (int j = 0; j < 4; j++) {
                int bl = blb + j;
                double d = xn[bl] + bnv - 2.0 * dv[j];
                stored(out, odist + ((size_t)(b0 + bl) * DIM_CODES + c) * BOOK_SIZE + s0 + sl, bf, d);
                if (d < bd[pb * 4 + j]) { bd[pb * 4 + j] = d; bsx[pb * 4 + j] = s0 + sl; }
            }
        }
    }
#pragma unroll
    for (int p = 0; p < 8; p++) {
        double d = bd[p];
        int s = bsx[p];
        for (int off = 32; off >= 1; off >>= 1) {
            double od = __shfl_xor(d, off, 64);
            int os = __shfl_xor(s, off, 64);
            if (od < d || (od == d && os < s)) { d = od; s = os; }
        }
        if (sl == 0)
            stored(out, oidx + (size_t)(b0 + wv * 8 + p) * DIM_CODES + c, bf, (double)s);
    }
}

extern "C" void kernel_launch(void* const* d_in, const int* in_sizes, int n_in,
                              void* d_out, int out_size, void* d_ws, size_t ws_size,
                              hipStream_t stream) {
    const void* x        = d_in[0];
    const void* codebook = d_in[1];
    const void* enc_w1   = d_in[2];
    const void* enc_b1   = d_in[3];
    const void* enc_w2   = d_in[4];
    const void* enc_b2   = d_in[5];
    const void* inf1_w   = d_in[6];
    const void* inf1_b   = d_in[7];
    const void* inf2_w1  = d_in[8];
    const void* inf2_b1  = d_in[9];
    const void* inf2_w2  = d_in[10];
    const void* inf2_b2  = d_in[11];
    const void* prior_w1 = d_in[12];
    const void* prior_b1 = d_in[13];
    const void* prior_w2 = d_in[14];
    const void* prior_b2 = d_in[15];
    const void* dec_w1   = d_in[16];
    const void* dec_b1   = d_in[17];
    const void* dec_w2   = d_in[18];
    const void* dec_b2   = d_in[19];

    // ---- fp32 workspace with aliasing (~26 MB) ----
    float* W0 = (float*)d_ws;
    float* inf1out = W0;                   // 512*512           [live to end]
    float* pfull   = inf1out + 262144;     // 512*1536          [live to end]
    float* dfull   = pfull + 786432;       // 512*1536          [live to end]
    float* cwr     = dfull + 786432;       // 512*4096          [live to end]
    float* bufA    = cwr + 2097152;        // 512*2048: h2, later dech
    float* bufB    = bufA + 1048576;       // 512*2048: p1, later d1
    float* bufC    = bufB + 1048576;       // 512*512: hmax
    double* bn     = (double*)(bufC + 393216);  // 64*1024 doubles
    int* dflag     = (int*)(bn + 65536);

    // ---- output slice element offsets (return order) ----
    const size_t o_cwrecon = 0;
    const size_t o_cwdist  = 2097152;
    const size_t o_idx     = 35651584;
    const size_t o_mu      = 35684352;
    const size_t o_logvar  = 35815424;
    const size_t o_dmu     = 35946496;
    const size_t o_dlogvar = 36339712;
    const size_t o_plogvar = 36732928;

    detect_kernel<<<1, 256, 0, stream>>>((const u16*)x, dflag);
    booknorm_kernel<<<256, 256, 0, stream>>>(codebook, bn, dflag);
    enc_kernel<<<dim3(8, BATCH), 256, 0, stream>>>(x, enc_w1, enc_b1, bufC, dflag);  // hmax -> bufC

    // h2 = hmax @ enc_w2^T
    gemm_kernel<<<dim3(32, 4), 256, 0, stream>>>(bufC, 512, 512, bufC, 512, 512, nullptr,
                                                 enc_w2, enc_b2, bufA, 2048, 0,
                                                 d_out, 0, 0, 0, 0, 0, 0, 0, 0, dflag);
    // inf1out = h2 @ inf1_w^T (mu | log_var) + fused mu/logvar stores
    gemm_kernel<<<dim3(8, 4), 256, 0, stream>>>(bufA, 2048, 2048, bufA, 2048, 2048, nullptr,
                                                inf1_w, inf1_b, inf1out, 512, 0,
                                                d_out, o_mu, 0, 256, 256,
                                                o_logvar, 256, 512, 256, dflag);
    // p1 = lrelu(z1 @ prior_w1^T); z1 = inf1out[:, :256]
    gemm_kernel<<<dim3(32, 4), 256, 0, stream>>>(inf1out, 512, 256, inf1out, 512, 256, nullptr,
                                                 prior_w1, prior_b1, bufB, 2048, 1,
                                                 d_out, 0, 0, 0, 0, 0, 0, 0, 0, dflag);
    // pfull = p1 @ prior_w2^T + fused plogvar store
    gemm_kernel<<<dim3(24, 4), 256, 0, stream>>>(bufB, 2048, 2048, bufB, 2048, 2048, nullptr,
                                                 prior_w2, prior_b2, pfull, 1536, 0,
                                                 d_out, o_plogvar, 768, 1536, 768,
                                                 0, 0, 0, 0, dflag);
    // d1 = lrelu(concat(z1, h2) @ inf2_w1^T)   (overwrites p1, dead)
    gemm_kernel<<<dim3(32, 4), 256, 0, stream>>>(inf1out, 512, 256, bufA, 2048, 2304, nullptr,
                                                 inf2_w1, inf2_b1, bufB, 2048, 1,
                                                 d_out, 0, 0, 0, 0, 0, 0, 0, 0, dflag);
    // dfull = d1 @ inf2_w2^T + fused dmu/dlogvar stores
    gemm_kernel<<<dim3(24, 4), 256, 0, stream>>>(bufB, 2048, 2048, bufB, 2048, 2048, nullptr,
                                                 inf2_w2, inf2_b2, dfull, 1536, 0,
                                                 d_out, o_dmu, 0, 768, 768,
                                                 o_dlogvar, 768, 1536, 768, dflag);
    // dech = lrelu((dfull[:, :768] + pfull[:, :768]) @ dec_w1^T)   (add fused via Aadd)
    gemm_kernel<<<dim3(32, 4), 256, 0, stream>>>(dfull, 1536, 768, dfull, 1536, 768, pfull,
                                                 dec_w1, dec_b1, bufA, 2048, 1,
                                                 d_out, 0, 0, 0, 0, 0, 0, 0, 0, dflag);
    // cwr = dech @ dec_w2^T + fused cwrecon store
    gemm_kernel<<<dim3(64, 4), 256, 0, stream>>>(bufA, 2048, 2048, bufA, 2048, 2048, nullptr,
                                                 dec_w2, dec_b2, cwr, 4096, 0,
                                                 d_out, o_cwrecon, 0, 4096, 4096,
                                                 0, 0, 0, 0, dflag);

    // fused distances + argmin (writes o_cwdist and o_idx directly; fp64 kept here)
    dist_kernel<<<dim3(64, 16), 256, 0, stream>>>(cwr, codebook, bn,
                                                  d_out, o_cwdist, o_idx, dflag);
}

// Round 5
// 1068.112 us; speedup vs baseline: 1.6743x; 1.6743x over previous
//
#include <hip/hip_runtime.h>
#include <hip/hip_bf16.h>

typedef __hip_bfloat16 bf16;
typedef unsigned short u16;

#define BATCH 512
#define CW_DIM 4096
#define DIM_CODES 64
#define BOOK_SIZE 1024
#define DIM_EMBED 64
#define ENC_H 512

// ---------------- dtype helpers (bf=1 -> bf16 inputs, bf=0 -> fp32) ----------------
__device__ __forceinline__ float bf2f(u16 u) {
    unsigned int x = ((unsigned int)u) << 16;
    return __uint_as_float(x);
}
__device__ __forceinline__ float loadf(const void* p, size_t i, int bf) {
    if (bf) return bf2f(((const u16*)p)[i]);
    return ((const float*)p)[i];
}
// vector load of 4 consecutive elements (i must be a multiple of 4)
__device__ __forceinline__ float4 load4(const void* p, size_t i, int bf) {
    if (bf) {
        const u16* q = (const u16*)p + i;
        uint2 raw = *reinterpret_cast<const uint2*>(q);
        float4 r;
        r.x = bf2f((u16)(raw.x & 0xFFFF));
        r.y = bf2f((u16)(raw.x >> 16));
        r.z = bf2f((u16)(raw.y & 0xFFFF));
        r.w = bf2f((u16)(raw.y >> 16));
        return r;
    }
    return *reinterpret_cast<const float4*>((const float*)p + i);
}
__device__ __forceinline__ void stored(void* p, size_t i, int bf, double v) {
    if (bf) ((bf16*)p)[i] = __float2bfloat16((float)v);
    else    ((float*)p)[i] = (float)v;
}
__device__ __forceinline__ u16 f2bfu(float v) {
    bf16 b = __float2bfloat16(v);
    return *reinterpret_cast<u16*>(&b);
}

// ---------------- dtype detector ----------------
__global__ void detect_kernel(const u16* __restrict__ x, int* __restrict__ flag) {
    __shared__ int hits;
    if (threadIdx.x == 0) hits = 0;
    __syncthreads();
    int h = 0;
    for (int i = threadIdx.x; i < 16384; i += 256) {
        u16 v = x[2 * i];
        if (((v >> 7) & 0xFF) == 0xFF) h++;
    }
    atomicAdd(&hits, h);
    __syncthreads();
    if (threadIdx.x == 0) *flag = (hits == 0) ? 1 : 0;  // 1 = bf16, 0 = fp32
}

// ---------------- codebook row norms (fp64, vectorized loads) ----------------
__global__ void booknorm_kernel(const void* __restrict__ book, double* __restrict__ bn,
                                const int* __restrict__ dflag) {
    const int bf = *dflag;
    int r = blockIdx.x * blockDim.x + threadIdx.x;
    if (r >= DIM_CODES * BOOK_SIZE) return;
    double acc = 0.0;
    for (int e = 0; e < DIM_EMBED; e += 4) {
        float4 v = load4(book, (size_t)r * DIM_EMBED + e, bf);
        acc = fma((double)v.x, (double)v.x, acc);
        acc = fma((double)v.y, (double)v.y, acc);
        acc = fma((double)v.z, (double)v.z, acc);
        acc = fma((double)v.w, (double)v.w, acc);
    }
    bn[r] = acc;
}

// ---------------- encoder conv + maxpool: 64c x 64h register-tiled mini-GEMM ----------------
__global__ __launch_bounds__(256) void enc_kernel(const void* __restrict__ x,
                                                  const void* __restrict__ w1,
                                                  const void* __restrict__ b1,
                                                  float* __restrict__ hmax,
                                                  const int* __restrict__ dflag) {
    const int bf = *dflag;
    __shared__ float xs_t[64][68];   // [e][c]
    __shared__ float wsh_t[64][68];  // [e][h]
    __shared__ float red[64][17];
    int t = threadIdx.x;
    int h0 = blockIdx.x * 64;
    int b = blockIdx.y;

    int cr = t >> 2;             // 0..63 (c row for x, h row for w1)
    int e0 = (t & 3) << 4;       // 0,16,32,48
    for (int q = 0; q < 4; q++) {
        int e = e0 + (q << 2);
        float4 xv = load4(x, (size_t)b * CW_DIM + cr * DIM_EMBED + e, bf);
        xs_t[e + 0][cr] = xv.x; xs_t[e + 1][cr] = xv.y;
        xs_t[e + 2][cr] = xv.z; xs_t[e + 3][cr] = xv.w;
        float4 wv = load4(w1, (size_t)(h0 + cr) * DIM_EMBED + e, bf);
        wsh_t[e + 0][cr] = wv.x; wsh_t[e + 1][cr] = wv.y;
        wsh_t[e + 2][cr] = wv.z; wsh_t[e + 3][cr] = wv.w;
    }
    __syncthreads();

    int th = t & 15, tc = t >> 4;   // thread tile: 4 c x 4 h
    float acc[4][4] = {};
    for (int e = 0; e < 64; e++) {
        float4 a4 = *(const float4*)&xs_t[e][tc << 2];
        float4 w4 = *(const float4*)&wsh_t[e][th << 2];
        float aa[4] = {a4.x, a4.y, a4.z, a4.w};
        float ww[4] = {w4.x, w4.y, w4.z, w4.w};
#pragma unroll
        for (int i = 0; i < 4; i++)
#pragma unroll
            for (int j = 0; j < 4; j++)
                acc[i][j] = fmaf(aa[i], ww[j], acc[i][j]);
    }
#pragma unroll
    for (int j = 0; j < 4; j++) {
        float bj = loadf(b1, h0 + (th << 2) + j, bf);
        float m = -1e30f;
#pragma unroll
        for (int i = 0; i < 4; i++) {
            float v = acc[i][j] + bj;
            v = v > 0.f ? v : 0.2f * v;
            m = fmaxf(m, v);
        }
        red[(th << 2) + j][tc] = m;
    }
    __syncthreads();
    if (t < 64) {
        float m = red[t][0];
        for (int k = 1; k < 16; k++) m = fmaxf(m, red[t][k]);
        hmax[(size_t)b * ENC_H + h0 + t] = m;
    }
}

// ---------------- fp32 GEMM: C[M,N] = act(A @ W^T + bias), 64x64 tile, 4x4/thread ----------------
// Double-buffered LDS + register prefetch: global loads for K-tile kt+1 are issued BEFORE the
// compute phase of kt (latency hides under 256 FMA wave-instrs), written to the alternate LDS
// buffer after compute; ONE barrier per K-iter.
// A logically [M,Ktot]: cols [0,K1) from A1 (stride lda1), rest from A2 (stride lda2).
// Aadd (optional, stride lda1): added elementwise to the A1 region (z2 = dfull+pfull fusion).
// Fused epilogue slice-stores: slice s writes C cols [c0,c1) to out[base + m*ostride + (n-c0)]
// in output dtype. Slice boundaries are multiples of 64 -> never straddle a thread's float4.
// Per-output accumulation order (kt asc, kk asc) identical to Round-3 version.
__global__ __launch_bounds__(256) void gemm_kernel(const float* __restrict__ A1, int lda1, int K1,
                                                   const float* __restrict__ A2, int lda2, int Ktot,
                                                   const float* __restrict__ Aadd,
                                                   const void* __restrict__ W,
                                                   const void* __restrict__ bias,
                                                   float* __restrict__ C, int N, int act,
                                                   void* __restrict__ out,
                                                   size_t s0base, int s0c0, int s0c1, int s0stride,
                                                   size_t s1base, int s1c0, int s1c1, int s1stride,
                                                   const int* __restrict__ dflag) {
    const int bf = *dflag;
    __shared__ float As[2][16][68];
    __shared__ float Ws[2][16][68];
    int t = threadIdx.x;
    int tx = t & 15, ty = t >> 4;
    int n0 = blockIdx.x * 64, m0 = blockIdx.y * 64;
    int mrow = t >> 2, kq = (t & 3) << 2;  // each thread stages one float4 of A and one of W
    float acc[4][4] = {};

    // ---- prefetch K-tile 0 into registers ----
    float4 av, wv;
    {
        int k = kq;
        if (k < K1) {
            av = *reinterpret_cast<const float4*>(A1 + (size_t)(m0 + mrow) * lda1 + k);
            if (Aadd) {
                float4 ad = *reinterpret_cast<const float4*>(Aadd + (size_t)(m0 + mrow) * lda1 + k);
                av.x += ad.x; av.y += ad.y; av.z += ad.z; av.w += ad.w;
            }
        } else {
            av = *reinterpret_cast<const float4*>(A2 + (size_t)(m0 + mrow) * lda2 + (k - K1));
        }
        wv = load4(W, (size_t)(n0 + mrow) * Ktot + k, bf);
    }
    As[0][kq + 0][mrow] = av.x; As[0][kq + 1][mrow] = av.y;
    As[0][kq + 2][mrow] = av.z; As[0][kq + 3][mrow] = av.w;
    Ws[0][kq + 0][mrow] = wv.x; Ws[0][kq + 1][mrow] = wv.y;
    Ws[0][kq + 2][mrow] = wv.z; Ws[0][kq + 3][mrow] = wv.w;
    __syncthreads();

    int buf = 0;
#pragma unroll 1
    for (int kt = 0; kt < Ktot; kt += 16) {
        int nxt = kt + 16;
        if (nxt < Ktot) {  // issue next tile's global loads early; latency hides under compute
            int k = nxt + kq;
            if (k < K1) {
                av = *reinterpret_cast<const float4*>(A1 + (size_t)(m0 + mrow) * lda1 + k);
                if (Aadd) {
                    float4 ad = *reinterpret_cast<const float4*>(Aadd + (size_t)(m0 + mrow) * lda1 + k);
                    av.x += ad.x; av.y += ad.y; av.z += ad.z; av.w += ad.w;
                }
            } else {
                av = *reinterpret_cast<const float4*>(A2 + (size_t)(m0 + mrow) * lda2 + (k - K1));
            }
            wv = load4(W, (size_t)(n0 + mrow) * Ktot + k, bf);
        }
#pragma unroll
        for (int kk = 0; kk < 16; kk++) {
            float4 a4 = *(const float4*)&As[buf][kk][ty << 2];
            float4 w4 = *(const float4*)&Ws[buf][kk][tx << 2];
            float a[4] = {a4.x, a4.y, a4.z, a4.w};
            float w[4] = {w4.x, w4.y, w4.z, w4.w};
#pragma unroll
            for (int i = 0; i < 4; i++)
#pragma unroll
                for (int j = 0; j < 4; j++)
                    acc[i][j] = fmaf(a[i], w[j], acc[i][j]);
        }
        if (nxt < Ktot) {
            int nb = buf ^ 1;  // readers of nb finished before the barrier that ended iter kt-1
            As[nb][kq + 0][mrow] = av.x; As[nb][kq + 1][mrow] = av.y;
            As[nb][kq + 2][mrow] = av.z; As[nb][kq + 3][mrow] = av.w;
            Ws[nb][kq + 0][mrow] = wv.x; Ws[nb][kq + 1][mrow] = wv.y;
            Ws[nb][kq + 2][mrow] = wv.z; Ws[nb][kq + 3][mrow] = wv.w;
            __syncthreads();
            buf = nb;
        }
    }

    int nbase = n0 + tx * 4;
    float b0 = loadf(bias, nbase + 0, bf), b1v = loadf(bias, nbase + 1, bf);
    float b2 = loadf(bias, nbase + 2, bf), b3 = loadf(bias, nbase + 3, bf);
#pragma unroll
    for (int i = 0; i < 4; i++) {
        int m = m0 + ty * 4 + i;
        float ov[4];
        ov[0] = acc[i][0] + b0; ov[1] = acc[i][1] + b1v;
        ov[2] = acc[i][2] + b2; ov[3] = acc[i][3] + b3;
        if (act) {
#pragma unroll
            for (int j = 0; j < 4; j++) ov[j] = ov[j] > 0.f ? ov[j] : 0.2f * ov[j];
        }
        float4 o = {ov[0], ov[1], ov[2], ov[3]};
        *reinterpret_cast<float4*>(C + (size_t)m * N + nbase) = o;
        if (nbase >= s0c0 && nbase < s0c1) {
            size_t off = s0base + (size_t)m * s0stride + (nbase - s0c0);
            if (bf) {
                ushort4 h = {f2bfu(ov[0]), f2bfu(ov[1]), f2bfu(ov[2]), f2bfu(ov[3])};
                *reinterpret_cast<ushort4*>((u16*)out + off) = h;
            } else {
                *reinterpret_cast<float4*>((float*)out + off) = o;
            }
        }
        if (nbase >= s1c0 && nbase < s1c1) {
            size_t off = s1base + (size_t)m * s1stride + (nbase - s1c0);
            if (bf) {
                ushort4 h = {f2bfu(ov[0]), f2bfu(ov[1]), f2bfu(ov[2]), f2bfu(ov[3])};
                *reinterpret_cast<ushort4*>((u16*)out + off) = h;
            } else {
                *reinterpret_cast<float4*>((float*)out + off) = o;
            }
        }
    }
}

// ---------------- fused cw_dist (fp64) + exact argmin ----------------
// grid (c=64, btile=16); block 256 = 4 waves; block covers 32 b-rows x 1024 s.
// Per thread: 8 b-rows as 2 groups of 4 scalar fp64 accumulators.
// #pragma unroll 1 on st-loop: prevents full-unroll + cross-barrier pipelining (spill hazard).
__global__ __launch_bounds__(256, 4) void dist_kernel(const float* __restrict__ cwr,
                                                      const void* __restrict__ book,
                                                      const double* __restrict__ bn,
                                                      void* __restrict__ out,
                                                      size_t odist, size_t oidx,
                                                      const int* __restrict__ dflag) {
    const int bf = *dflag;
    __shared__ double xs[32][64];   // 16 KB
    __shared__ double xn[32];
    __shared__ float bs[64][66];    // float2-aligned; ~2-way eff. bank aliasing (free)
    int t = threadIdx.x;
    int c = blockIdx.x;
    int b0 = blockIdx.y * 32;
    int sl = t & 63, wv = t >> 6;

    for (int i = t; i < 32 * 64; i += 256) {
        int bl = i >> 6, e = i & 63;
        xs[bl][e] = (double)cwr[(size_t)(b0 + bl) * CW_DIM + c * DIM_EMBED + e];
    }
    __syncthreads();
    if (t < 32) {
        double a = 0.0;
        for (int e = 0; e < 64; e++) a = fma(xs[t][e], xs[t][e], a);
        xn[t] = a;
    }

    double bd[8];
    int bsx[8];
#pragma unroll
    for (int p = 0; p < 8; p++) { bd[p] = 1e300; bsx[p] = 0; }

#pragma unroll 1
    for (int st = 0; st < 16; st++) {
        int s0 = st * 64;
        __syncthreads();  // previous-tile readers done (and xn visible on st==0)
#pragma unroll
        for (int i4 = t; i4 < 1024; i4 += 256) {
            int srow = i4 >> 4, e4 = (i4 & 15) << 2;
            float4 v = load4(book, ((size_t)c * BOOK_SIZE + s0 + srow) * DIM_EMBED + e4, bf);
            bs[srow][e4 + 0] = v.x; bs[srow][e4 + 1] = v.y;
            bs[srow][e4 + 2] = v.z; bs[srow][e4 + 3] = v.w;
        }
        __syncthreads();
        double bnv = bn[(size_t)c * BOOK_SIZE + s0 + sl];
#pragma unroll
        for (int pb = 0; pb < 2; pb++) {   // fully unrolled (2): bd/bsx indices compile-time
            int blb = wv * 8 + pb * 4;
            double a0 = 0.0, a1 = 0.0, a2 = 0.0, a3 = 0.0;
#pragma unroll 8
            for (int e = 0; e < 64; e += 2) {
                float2 bv = *(const float2*)&bs[sl][e];
                double bv0 = (double)bv.x, bv1 = (double)bv.y;
                double2 x0 = *(const double2*)&xs[blb + 0][e];
                double2 x1 = *(const double2*)&xs[blb + 1][e];
                double2 x2 = *(const double2*)&xs[blb + 2][e];
                double2 x3 = *(const double2*)&xs[blb + 3][e];
                a0 = fma(x0.x, bv0, a0); a0 = fma(x0.y, bv1, a0);
                a1 = fma(x1.x, bv0, a1); a1 = fma(x1.y, bv1, a1);
                a2 = fma(x2.x, bv0, a2); a2 = fma(x2.y, bv1, a2);
                a3 = fma(x3.x, bv0, a3); a3 = fma(x3.y, bv1, a3);
            }
            double dv[4];
            dv[0] = a0; dv[1] = a1; dv[2] = a2; dv[3] = a3;
#pragma unroll
            for (int j = 0; j < 4; j++) {
                int bl = blb + j;
                double d = xn[bl] + bnv - 2.0 * dv[j];
                stored(out, odist + ((size_t)(b0 + bl) * DIM_CODES + c) * BOOK_SIZE + s0 + sl, bf, d);
                if (d < bd[pb * 4 + j]) { bd[pb * 4 + j] = d; bsx[pb * 4 + j] = s0 + sl; }
            }
        }
    }
#pragma unroll
    for (int p = 0; p < 8; p++) {
        double d = bd[p];
        int s = bsx[p];
        for (int off = 32; off >= 1; off >>= 1) {
            double od = __shfl_xor(d, off, 64);
            int os = __shfl_xor(s, off, 64);
            if (od < d || (od == d && os < s)) { d = od; s = os; }
        }
        if (sl == 0)
            stored(out, oidx + (size_t)(b0 + wv * 8 + p) * DIM_CODES + c, bf, (double)s);
    }
}

extern "C" void kernel_launch(void* const* d_in, const int* in_sizes, int n_in,
                              void* d_out, int out_size, void* d_ws, size_t ws_size,
                              hipStream_t stream) {
    const void* x        = d_in[0];
    const void* codebook = d_in[1];
    const void* enc_w1   = d_in[2];
    const void* enc_b1   = d_in[3];
    const void* enc_w2   = d_in[4];
    const void* enc_b2   = d_in[5];
    const void* inf1_w   = d_in[6];
    const void* inf1_b   = d_in[7];
    const void* inf2_w1  = d_in[8];
    const void* inf2_b1  = d_in[9];
    const void* inf2_w2  = d_in[10];
    const void* inf2_b2  = d_in[11];
    const void* prior_w1 = d_in[12];
    const void* prior_b1 = d_in[13];
    const void* prior_w2 = d_in[14];
    const void* prior_b2 = d_in[15];
    const void* dec_w1   = d_in[16];
    const void* dec_b1   = d_in[17];
    const void* dec_w2   = d_in[18];
    const void* dec_b2   = d_in[19];

    // ---- fp32 workspace with aliasing (~26 MB) ----
    float* W0 = (float*)d_ws;
    float* inf1out = W0;                   // 512*512           [live to end]
    float* pfull   = inf1out + 262144;     // 512*1536          [live to end]
    float* dfull   = pfull + 786432;       // 512*1536          [live to end]
    float* cwr     = dfull + 786432;       // 512*4096          [live to end]
    float* bufA    = cwr + 2097152;        // 512*2048: h2, later dech
    float* bufB    = bufA + 1048576;       // 512*2048: p1, later d1
    float* bufC    = bufB + 1048576;       // 512*512: hmax
    double* bn     = (double*)(bufC + 393216);  // 64*1024 doubles
    int* dflag     = (int*)(bn + 65536);

    // ---- output slice element offsets (return order) ----
    const size_t o_cwrecon = 0;
    const size_t o_cwdist  = 2097152;
    const size_t o_idx     = 35651584;
    const size_t o_mu      = 35684352;
    const size_t o_logvar  = 35815424;
    const size_t o_dmu     = 35946496;
    const size_t o_dlogvar = 36339712;
    const size_t o_plogvar = 36732928;

    detect_kernel<<<1, 256, 0, stream>>>((const u16*)x, dflag);
    booknorm_kernel<<<256, 256, 0, stream>>>(codebook, bn, dflag);
    enc_kernel<<<dim3(8, BATCH), 256, 0, stream>>>(x, enc_w1, enc_b1, bufC, dflag);  // hmax -> bufC

    // h2 = hmax @ enc_w2^T
    gemm_kernel<<<dim3(32, 8), 256, 0, stream>>>(bufC, 512, 512, bufC, 512, 512, nullptr,
                                                 enc_w2, enc_b2, bufA, 2048, 0,
                                                 d_out, 0, 0, 0, 0, 0, 0, 0, 0, dflag);
    // inf1out = h2 @ inf1_w^T (mu | log_var) + fused mu/logvar stores
    gemm_kernel<<<dim3(8, 8), 256, 0, stream>>>(bufA, 2048, 2048, bufA, 2048, 2048, nullptr,
                                                inf1_w, inf1_b, inf1out, 512, 0,
                                                d_out, o_mu, 0, 256, 256,
                                                o_logvar, 256, 512, 256, dflag);
    // p1 = lrelu(z1 @ prior_w1^T); z1 = inf1out[:, :256]
    gemm_kernel<<<dim3(32, 8), 256, 0, stream>>>(inf1out, 512, 256, inf1out, 512, 256, nullptr,
                                                 prior_w1, prior_b1, bufB, 2048, 1,
                                                 d_out, 0, 0, 0, 0, 0, 0, 0, 0, dflag);
    // pfull = p1 @ prior_w2^T + fused plogvar store
    gemm_kernel<<<dim3(24, 8), 256, 0, stream>>>(bufB, 2048, 2048, bufB, 2048, 2048, nullptr,
                                                 prior_w2, prior_b2, pfull, 1536, 0,
                                                 d_out, o_plogvar, 768, 1536, 768,
                                                 0, 0, 0, 0, dflag);
    // d1 = lrelu(concat(z1, h2) @ inf2_w1^T)   (overwrites p1, dead)
    gemm_kernel<<<dim3(32, 8), 256, 0, stream>>>(inf1out, 512, 256, bufA, 2048, 2304, nullptr,
                                                 inf2_w1, inf2_b1, bufB, 2048, 1,
                                                 d_out, 0, 0, 0, 0, 0, 0, 0, 0, dflag);
    // dfull = d1 @ inf2_w2^T + fused dmu/dlogvar stores
    gemm_kernel<<<dim3(24, 8), 256, 0, stream>>>(bufB, 2048, 2048, bufB, 2048, 2048, nullptr,
                                                 inf2_w2, inf2_b2, dfull, 1536, 0,
                                                 d_out, o_dmu, 0, 768, 768,
                                                 o_dlogvar, 768, 1536, 768, dflag);
    // dech = lrelu((dfull[:, :768] + pfull[:, :768]) @ dec_w1^T)   (add fused via Aadd)
    gemm_kernel<<<dim3(32, 8), 256, 0, stream>>>(dfull, 1536, 768, dfull, 1536, 768, pfull,
                                                 dec_w1, dec_b1, bufA, 2048, 1,
                                                 d_out, 0, 0, 0, 0, 0, 0, 0, 0, dflag);
    // cwr = dech @ dec_w2^T + fused cwrecon store
    gemm_kernel<<<dim3(64, 8), 256, 0, stream>>>(bufA, 2048, 2048, bufA, 2048, 2048, nullptr,
                                                 dec_w2, dec_b2, cwr, 4096, 0,
                                                 d_out, o_cwrecon, 0, 4096, 4096,
                                                 0, 0, 0, 0, dflag);

    // fused distances + argmin (writes o_cwdist and o_idx directly; fp64 kept here)
    dist_kernel<<<dim3(64, 16), 256, 0, stream>>>(cwr, codebook, bn,
                                                  d_out, o_cwdist, o_idx, dflag);
}

// Round 6
// 1021.084 us; speedup vs baseline: 1.7514x; 1.0461x over previous
//
#include <hip/hip_runtime.h>
#include <hip/hip_bf16.h>

typedef __hip_bfloat16 bf16;
typedef unsigned short u16;

#define BATCH 512
#define CW_DIM 4096
#define DIM_CODES 64
#define BOOK_SIZE 1024
#define DIM_EMBED 64
#define ENC_H 512

// ---------------- dtype helpers (bf=1 -> bf16 inputs, bf=0 -> fp32) ----------------
__device__ __forceinline__ float bf2f(u16 u) {
    unsigned int x = ((unsigned int)u) << 16;
    return __uint_as_float(x);
}
__device__ __forceinline__ float loadf(const void* p, size_t i, int bf) {
    if (bf) return bf2f(((const u16*)p)[i]);
    return ((const float*)p)[i];
}
// vector load of 4 consecutive elements (i must be a multiple of 4)
__device__ __forceinline__ float4 load4(const void* p, size_t i, int bf) {
    if (bf) {
        const u16* q = (const u16*)p + i;
        uint2 raw = *reinterpret_cast<const uint2*>(q);
        float4 r;
        r.x = bf2f((u16)(raw.x & 0xFFFF));
        r.y = bf2f((u16)(raw.x >> 16));
        r.z = bf2f((u16)(raw.y & 0xFFFF));
        r.w = bf2f((u16)(raw.y >> 16));
        return r;
    }
    return *reinterpret_cast<const float4*>((const float*)p + i);
}
__device__ __forceinline__ void stored(void* p, size_t i, int bf, double v) {
    if (bf) ((bf16*)p)[i] = __float2bfloat16((float)v);
    else    ((float*)p)[i] = (float)v;
}
__device__ __forceinline__ u16 f2bfu(float v) {
    bf16 b = __float2bfloat16(v);
    return *reinterpret_cast<u16*>(&b);
}

// ---------------- dtype detector ----------------
__global__ void detect_kernel(const u16* __restrict__ x, int* __restrict__ flag) {
    __shared__ int hits;
    if (threadIdx.x == 0) hits = 0;
    __syncthreads();
    int h = 0;
    for (int i = threadIdx.x; i < 16384; i += 256) {
        u16 v = x[2 * i];
        if (((v >> 7) & 0xFF) == 0xFF) h++;
    }
    atomicAdd(&hits, h);
    __syncthreads();
    if (threadIdx.x == 0) *flag = (hits == 0) ? 1 : 0;  // 1 = bf16, 0 = fp32
}

// ---------------- codebook row norms (fp64, vectorized loads) ----------------
__global__ void booknorm_kernel(const void* __restrict__ book, double* __restrict__ bn,
                                const int* __restrict__ dflag) {
    const int bf = *dflag;
    int r = blockIdx.x * blockDim.x + threadIdx.x;
    if (r >= DIM_CODES * BOOK_SIZE) return;
    double acc = 0.0;
    for (int e = 0; e < DIM_EMBED; e += 4) {
        float4 v = load4(book, (size_t)r * DIM_EMBED + e, bf);
        acc = fma((double)v.x, (double)v.x, acc);
        acc = fma((double)v.y, (double)v.y, acc);
        acc = fma((double)v.z, (double)v.z, acc);
        acc = fma((double)v.w, (double)v.w, acc);
    }
    bn[r] = acc;
}

// ---------------- encoder conv + maxpool: 64c x 64h register-tiled mini-GEMM ----------------
__global__ __launch_bounds__(256) void enc_kernel(const void* __restrict__ x,
                                                  const void* __restrict__ w1,
                                                  const void* __restrict__ b1,
                                                  float* __restrict__ hmax,
                                                  const int* __restrict__ dflag) {
    const int bf = *dflag;
    __shared__ float xs_t[64][68];   // [e][c]
    __shared__ float wsh_t[64][68];  // [e][h]
    __shared__ float red[64][17];
    int t = threadIdx.x;
    int h0 = blockIdx.x * 64;
    int b = blockIdx.y;

    int cr = t >> 2;             // 0..63 (c row for x, h row for w1)
    int e0 = (t & 3) << 4;       // 0,16,32,48
    for (int q = 0; q < 4; q++) {
        int e = e0 + (q << 2);
        float4 xv = load4(x, (size_t)b * CW_DIM + cr * DIM_EMBED + e, bf);
        xs_t[e + 0][cr] = xv.x; xs_t[e + 1][cr] = xv.y;
        xs_t[e + 2][cr] = xv.z; xs_t[e + 3][cr] = xv.w;
        float4 wv = load4(w1, (size_t)(h0 + cr) * DIM_EMBED + e, bf);
        wsh_t[e + 0][cr] = wv.x; wsh_t[e + 1][cr] = wv.y;
        wsh_t[e + 2][cr] = wv.z; wsh_t[e + 3][cr] = wv.w;
    }
    __syncthreads();

    int th = t & 15, tc = t >> 4;   // thread tile: 4 c x 4 h
    float acc[4][4] = {};
    for (int e = 0; e < 64; e++) {
        float4 a4 = *(const float4*)&xs_t[e][tc << 2];
        float4 w4 = *(const float4*)&wsh_t[e][th << 2];
        float aa[4] = {a4.x, a4.y, a4.z, a4.w};
        float ww[4] = {w4.x, w4.y, w4.z, w4.w};
#pragma unroll
        for (int i = 0; i < 4; i++)
#pragma unroll
            for (int j = 0; j < 4; j++)
                acc[i][j] = fmaf(aa[i], ww[j], acc[i][j]);
    }
#pragma unroll
    for (int j = 0; j < 4; j++) {
        float bj = loadf(b1, h0 + (th << 2) + j, bf);
        float m = -1e30f;
#pragma unroll
        for (int i = 0; i < 4; i++) {
            float v = acc[i][j] + bj;
            v = v > 0.f ? v : 0.2f * v;
            m = fmaxf(m, v);
        }
        red[(th << 2) + j][tc] = m;
    }
    __syncthreads();
    if (t < 64) {
        float m = red[t][0];
        for (int k = 1; k < 16; k++) m = fmaxf(m, red[t][k]);
        hmax[(size_t)b * ENC_H + h0 + t] = m;
    }
}

// ---------------- GEMM descriptor + body (64x64 tile, 4x4/thread, dbuf + reg prefetch) ----------
struct GDesc {
    const float* A1; const float* A2; const float* Aadd;
    const void* W; const void* bias; float* C;
    int lda1, K1, lda2, Ktot, N, act, nbx, pad;
    size_t s0base; int s0c0, s0c1, s0stride;
    size_t s1base; int s1c0, s1c1, s1stride;
};

__device__ __forceinline__ void gemm_body(const GDesc& g, int bx, int by,
                                          void* __restrict__ out, const int bf) {
    __shared__ float As[2][16][68];
    __shared__ float Ws[2][16][68];
    int t = threadIdx.x;
    int tx = t & 15, ty = t >> 4;
    int n0 = bx * 64, m0 = by * 64;
    int mrow = t >> 2, kq = (t & 3) << 2;  // each thread stages one float4 of A and one of W
    float acc[4][4] = {};

    // ---- prefetch K-tile 0 ----
    float4 av, wv;
    {
        int k = kq;
        if (k < g.K1) {
            av = *reinterpret_cast<const float4*>(g.A1 + (size_t)(m0 + mrow) * g.lda1 + k);
            if (g.Aadd) {
                float4 ad = *reinterpret_cast<const float4*>(g.Aadd + (size_t)(m0 + mrow) * g.lda1 + k);
                av.x += ad.x; av.y += ad.y; av.z += ad.z; av.w += ad.w;
            }
        } else {
            av = *reinterpret_cast<const float4*>(g.A2 + (size_t)(m0 + mrow) * g.lda2 + (k - g.K1));
        }
        wv = load4(g.W, (size_t)(n0 + mrow) * g.Ktot + k, bf);
    }
    As[0][kq + 0][mrow] = av.x; As[0][kq + 1][mrow] = av.y;
    As[0][kq + 2][mrow] = av.z; As[0][kq + 3][mrow] = av.w;
    Ws[0][kq + 0][mrow] = wv.x; Ws[0][kq + 1][mrow] = wv.y;
    Ws[0][kq + 2][mrow] = wv.z; Ws[0][kq + 3][mrow] = wv.w;
    __syncthreads();

    int buf = 0;
#pragma unroll 1
    for (int kt = 0; kt < g.Ktot; kt += 16) {
        int nxt = kt + 16;
        if (nxt < g.Ktot) {  // issue next tile's global loads early
            int k = nxt + kq;
            if (k < g.K1) {
                av = *reinterpret_cast<const float4*>(g.A1 + (size_t)(m0 + mrow) * g.lda1 + k);
                if (g.Aadd) {
                    float4 ad = *reinterpret_cast<const float4*>(g.Aadd + (size_t)(m0 + mrow) * g.lda1 + k);
                    av.x += ad.x; av.y += ad.y; av.z += ad.z; av.w += ad.w;
                }
            } else {
                av = *reinterpret_cast<const float4*>(g.A2 + (size_t)(m0 + mrow) * g.lda2 + (k - g.K1));
            }
            wv = load4(g.W, (size_t)(n0 + mrow) * g.Ktot + k, bf);
        }
#pragma unroll
        for (int kk = 0; kk < 16; kk++) {
            float4 a4 = *(const float4*)&As[buf][kk][ty << 2];
            float4 w4 = *(const float4*)&Ws[buf][kk][tx << 2];
            float a[4] = {a4.x, a4.y, a4.z, a4.w};
            float w[4] = {w4.x, w4.y, w4.z, w4.w};
#pragma unroll
            for (int i = 0; i < 4; i++)
#pragma unroll
                for (int j = 0; j < 4; j++)
                    acc[i][j] = fmaf(a[i], w[j], acc[i][j]);
        }
        if (nxt < g.Ktot) {
            int nb = buf ^ 1;
            As[nb][kq + 0][mrow] = av.x; As[nb][kq + 1][mrow] = av.y;
            As[nb][kq + 2][mrow] = av.z; As[nb][kq + 3][mrow] = av.w;
            Ws[nb][kq + 0][mrow] = wv.x; Ws[nb][kq + 1][mrow] = wv.y;
            Ws[nb][kq + 2][mrow] = wv.z; Ws[nb][kq + 3][mrow] = wv.w;
            __syncthreads();
            buf = nb;
        }
    }

    int nbase = n0 + tx * 4;
    float b0 = loadf(g.bias, nbase + 0, bf), b1v = loadf(g.bias, nbase + 1, bf);
    float b2 = loadf(g.bias, nbase + 2, bf), b3 = loadf(g.bias, nbase + 3, bf);
#pragma unroll
    for (int i = 0; i < 4; i++) {
        int m = m0 + ty * 4 + i;
        float ov[4];
        ov[0] = acc[i][0] + b0; ov[1] = acc[i][1] + b1v;
        ov[2] = acc[i][2] + b2; ov[3] = acc[i][3] + b3;
        if (g.act) {
#pragma unroll
            for (int j = 0; j < 4; j++) ov[j] = ov[j] > 0.f ? ov[j] : 0.2f * ov[j];
        }
        float4 o = {ov[0], ov[1], ov[2], ov[3]};
        *reinterpret_cast<float4*>(g.C + (size_t)m * g.N + nbase) = o;
        if (nbase >= g.s0c0 && nbase < g.s0c1) {
            size_t off = g.s0base + (size_t)m * g.s0stride + (nbase - g.s0c0);
            if (bf) {
                ushort4 h = {f2bfu(ov[0]), f2bfu(ov[1]), f2bfu(ov[2]), f2bfu(ov[3])};
                *reinterpret_cast<ushort4*>((u16*)out + off) = h;
            } else {
                *reinterpret_cast<float4*>((float*)out + off) = o;
            }
        }
        if (nbase >= g.s1c0 && nbase < g.s1c1) {
            size_t off = g.s1base + (size_t)m * g.s1stride + (nbase - g.s1c0);
            if (bf) {
                ushort4 h = {f2bfu(ov[0]), f2bfu(ov[1]), f2bfu(ov[2]), f2bfu(ov[3])};
                *reinterpret_cast<ushort4*>((u16*)out + off) = h;
            } else {
                *reinterpret_cast<float4*>((float*)out + off) = o;
            }
        }
    }
}

__global__ __launch_bounds__(256) void gemm_kernel(GDesc g, void* __restrict__ out,
                                                   const int* __restrict__ dflag) {
    gemm_body(g, blockIdx.x, blockIdx.y, out, *dflag);
}

// two independent GEMMs in one dispatch; block-uniform descriptor select
__global__ __launch_bounds__(256) void gemm2_kernel(GDesc g0, GDesc g1, void* __restrict__ out,
                                                    const int* __restrict__ dflag) {
    const int bf = *dflag;
    bool first = (int)blockIdx.x < g0.nbx;
    GDesc g = first ? g0 : g1;
    int bx = first ? blockIdx.x : blockIdx.x - g0.nbx;
    gemm_body(g, bx, blockIdx.y, out, bf);
}

// ---------------- fused cw_dist (fp64) + exact argmin ----------------
// grid (c=64, btile=16); block 256 = 4 waves; block covers 32 b-rows x 1024 s.
// bs double-buffered with register-staged prefetch -> ONE barrier per s-tile;
// bn load issued at loop top, consumed after the FMA block (latency hidden).
// Inner compute identical to the proven Round-3 structure (2x4 scalar fp64 acc).
// #pragma unroll 1 on st-loop: prevents full-unroll spill (Round-2 lesson).
__global__ __launch_bounds__(256, 4) void dist_kernel(const float* __restrict__ cwr,
                                                      const void* __restrict__ book,
                                                      const double* __restrict__ bn,
                                                      void* __restrict__ out,
                                                      size_t odist, size_t oidx,
                                                      const int* __restrict__ dflag) {
    const int bf = *dflag;
    __shared__ double xs[32][64];     // 16 KB
    __shared__ double xn[32];
    __shared__ float bs[2][64][66];   // 2 x 16.5 KB, double-buffered
    int t = threadIdx.x;
    int c = blockIdx.x;
    int b0 = blockIdx.y * 32;
    int sl = t & 63, wv = t >> 6;

    for (int i = t; i < 32 * 64; i += 256) {
        int bl = i >> 6, e = i & 63;
        xs[bl][e] = (double)cwr[(size_t)(b0 + bl) * CW_DIM + c * DIM_EMBED + e];
    }
    // stage s-tile 0 into bs[0]
    {
        size_t base = (size_t)c * BOOK_SIZE * DIM_EMBED;
        int i4, srow, e4;
        i4 = t;       srow = i4 >> 4; e4 = (i4 & 15) << 2;
        float4 v0 = load4(book, base + (size_t)srow * DIM_EMBED + e4, bf);
        bs[0][srow][e4 + 0] = v0.x; bs[0][srow][e4 + 1] = v0.y;
        bs[0][srow][e4 + 2] = v0.z; bs[0][srow][e4 + 3] = v0.w;
        i4 = t + 256; srow = i4 >> 4; e4 = (i4 & 15) << 2;
        float4 v1 = load4(book, base + (size_t)srow * DIM_EMBED + e4, bf);
        bs[0][srow][e4 + 0] = v1.x; bs[0][srow][e4 + 1] = v1.y;
        bs[0][srow][e4 + 2] = v1.z; bs[0][srow][e4 + 3] = v1.w;
        i4 = t + 512; srow = i4 >> 4; e4 = (i4 & 15) << 2;
        float4 v2 = load4(book, base + (size_t)srow * DIM_EMBED + e4, bf);
        bs[0][srow][e4 + 0] = v2.x; bs[0][srow][e4 + 1] = v2.y;
        bs[0][srow][e4 + 2] = v2.z; bs[0][srow][e4 + 3] = v2.w;
        i4 = t + 768; srow = i4 >> 4; e4 = (i4 & 15) << 2;
        float4 v3 = load4(book, base + (size_t)srow * DIM_EMBED + e4, bf);
        bs[0][srow][e4 + 0] = v3.x; bs[0][srow][e4 + 1] = v3.y;
        bs[0][srow][e4 + 2] = v3.z; bs[0][srow][e4 + 3] = v3.w;
    }
    __syncthreads();
    if (t < 32) {
        double a = 0.0;
        for (int e = 0; e < 64; e++) a = fma(xs[t][e], xs[t][e], a);
        xn[t] = a;
    }
    __syncthreads();

    double bd[8];
    int bsx[8];
#pragma unroll
    for (int p = 0; p < 8; p++) { bd[p] = 1e300; bsx[p] = 0; }

#pragma unroll 1
    for (int st = 0; st < 16; st++) {
        int s0 = st * 64;
        int cur = st & 1, nb = cur ^ 1;
        // early-issue: bn for this tile (consumed ~1600 FMA-cycles later)
        double bnv = bn[(size_t)c * BOOK_SIZE + s0 + sl];
        // early-issue: next tile's book loads into registers
        float4 pf0, pf1, pf2, pf3;
        int s0n = s0 + 64;
        if (st < 15) {
            size_t base = ((size_t)c * BOOK_SIZE + s0n) * DIM_EMBED;
            int i4, srow, e4;
            i4 = t;       srow = i4 >> 4; e4 = (i4 & 15) << 2;
            pf0 = load4(book, base + (size_t)srow * DIM_EMBED + e4, bf);
            i4 = t + 256; srow = i4 >> 4; e4 = (i4 & 15) << 2;
            pf1 = load4(book, base + (size_t)srow * DIM_EMBED + e4, bf);
            i4 = t + 512; srow = i4 >> 4; e4 = (i4 & 15) << 2;
            pf2 = load4(book, base + (size_t)srow * DIM_EMBED + e4, bf);
            i4 = t + 768; srow = i4 >> 4; e4 = (i4 & 15) << 2;
            pf3 = load4(book, base + (size_t)srow * DIM_EMBED + e4, bf);
        }
#pragma unroll
        for (int pb = 0; pb < 2; pb++) {   // fully unrolled (2): bd/bsx indices compile-time
            int blb = wv * 8 + pb * 4;
            double a0 = 0.0, a1 = 0.0, a2 = 0.0, a3 = 0.0;
#pragma unroll 8
            for (int e = 0; e < 64; e += 2) {
                float2 bv = *(const float2*)&bs[cur][sl][e];
                double bv0 = (double)bv.x, bv1 = (double)bv.y;
                double2 x0 = *(const double2*)&xs[blb + 0][e];
                double2 x1 = *(const double2*)&xs[blb + 1][e];
                double2 x2 = *(const double2*)&xs[blb + 2][e];
                double2 x3 = *(const double2*)&xs[blb + 3][e];
                a0 = fma(x0.x, bv0, a0); a0 = fma(x0.y, bv1, a0);
                a1 = fma(x1.x, bv0, a1); a1 = fma(x1.y, bv1, a1);
                a2 = fma(x2.x, bv0, a2); a2 = fma(x2.y, bv1, a2);
                a3 = fma(x3.x, bv0, a3); a3 = fma(x3.y, bv1, a3);
            }
            double dv[4];
            dv[0] = a0; dv[1] = a1; dv[2] = a2; dv[3] = a3;
#pragma unroll
            for (int j = 0; j < 4; j++) {
                int bl = blb + j;
                double d = xn[bl] + bnv - 2.0 * dv[j];
                stored(out, odist + ((size_t)(b0 + bl) * DIM_CODES + c) * BOOK_SIZE + s0 + sl, bf, d);
                if (d < bd[pb * 4 + j]) { bd[pb * 4 + j] = d; bsx[pb * 4 + j] = s0 + sl; }
            }
        }
        if (st < 15) {  // write prefetched tile into the alternate buffer
            int i4, srow, e4;
            i4 = t;       srow = i4 >> 4; e4 = (i4 & 15) << 2;
            bs[nb][srow][e4 + 0] = pf0.x; bs[nb][srow][e4 + 1] = pf0.y;
            bs[nb][srow][e4 + 2] = pf0.z; bs[nb][srow][e4 + 3] = pf0.w;
            i4 = t + 256; srow = i4 >> 4; e4 = (i4 & 15) << 2;
            bs[nb][srow][e4 + 0] = pf1.x; bs[nb][srow][e4 + 1] = pf1.y;
            bs[nb][srow][e4 + 2] = pf1.z; bs[nb][srow][e4 + 3] = pf1.w;
            i4 = t + 512; srow = i4 >> 4; e4 = (i4 & 15) << 2;
            bs[nb][srow][e4 + 0] = pf2.x; bs[nb][srow][e4 + 1] = pf2.y;
            bs[nb][srow][e4 + 2] = pf2.z; bs[nb][srow][e4 + 3] = pf2.w;
            i4 = t + 768; srow = i4 >> 4; e4 = (i4 & 15) << 2;
            bs[nb][srow][e4 + 0] = pf3.x; bs[nb][srow][e4 + 1] = pf3.y;
            bs[nb][srow][e4 + 2] = pf3.z; bs[nb][srow][e4 + 3] = pf3.w;
            __syncthreads();
        }
    }
#pragma unroll
    for (int p = 0; p < 8; p++) {
        double d = bd[p];
        int s = bsx[p];
        for (int off = 32; off >= 1; off >>= 1) {
            double od = __shfl_xor(d, off, 64);
            int os = __shfl_xor(s, off, 64);
            if (od < d || (od == d && os < s)) { d = od; s = os; }
        }
        if (sl == 0)
            stored(out, oidx + (size_t)(b0 + wv * 8 + p) * DIM_CODES + c, bf, (double)s);
    }
}

extern "C" void kernel_launch(void* const* d_in, const int* in_sizes, int n_in,
                              void* d_out, int out_size, void* d_ws, size_t ws_size,
                              hipStream_t stream) {
    const void* x        = d_in[0];
    const void* codebook = d_in[1];
    const void* enc_w1   = d_in[2];
    const void* enc_b1   = d_in[3];
    const void* enc_w2   = d_in[4];
    const void* enc_b2   = d_in[5];
    const void* inf1_w   = d_in[6];
    const void* inf1_b   = d_in[7];
    const void* inf2_w1  = d_in[8];
    const void* inf2_b1  = d_in[9];
    const void* inf2_w2  = d_in[10];
    const void* inf2_b2  = d_in[11];
    const void* prior_w1 = d_in[12];
    const void* prior_b1 = d_in[13];
    const void* prior_w2 = d_in[14];
    const void* prior_b2 = d_in[15];
    const void* dec_w1   = d_in[16];
    const void* dec_b1   = d_in[17];
    const void* dec_w2   = d_in[18];
    const void* dec_b2   = d_in[19];

    // ---- fp32 workspace with aliasing (~30 MB) ----
    float* W0 = (float*)d_ws;
    float* inf1out = W0;                   // 512*512           [live to end]
    float* pfull   = inf1out + 262144;     // 512*1536          [live to end]
    float* dfull   = pfull + 786432;       // 512*1536          [live to end]
    float* cwr     = dfull + 786432;       // 512*4096          [live to end]
    float* bufA    = cwr + 2097152;        // 512*2048: h2, later dech
    float* bufB    = bufA + 1048576;       // 512*2048: p1
    float* bufD    = bufB + 1048576;       // 512*2048: d1 (separate: p1/d1 run concurrently)
    float* bufC    = bufD + 1048576;       // 512*512: hmax
    double* bn     = (double*)(bufC + 262144);  // 64*1024 doubles
    int* dflag     = (int*)(bn + 65536);

    // ---- output slice element offsets (return order) ----
    const size_t o_cwrecon = 0;
    const size_t o_cwdist  = 2097152;
    const size_t o_idx     = 35651584;
    const size_t o_mu      = 35684352;
    const size_t o_logvar  = 35815424;
    const size_t o_dmu     = 35946496;
    const size_t o_dlogvar = 36339712;
    const size_t o_plogvar = 36732928;

    detect_kernel<<<1, 256, 0, stream>>>((const u16*)x, dflag);
    booknorm_kernel<<<256, 256, 0, stream>>>(codebook, bn, dflag);
    enc_kernel<<<dim3(8, BATCH), 256, 0, stream>>>(x, enc_w1, enc_b1, bufC, dflag);  // hmax -> bufC

    GDesc g, ga, gb;
    // h2 = hmax @ enc_w2^T
    g = {bufC, bufC, nullptr, enc_w2, enc_b2, bufA,
         512, 512, 512, 512, 2048, 0, 32, 0,
         0, 0, 0, 0, 0, 0, 0, 0};
    gemm_kernel<<<dim3(32, 8), 256, 0, stream>>>(g, d_out, dflag);
    // inf1out = h2 @ inf1_w^T (mu | log_var) + fused mu/logvar stores
    g = {bufA, bufA, nullptr, inf1_w, inf1_b, inf1out,
         2048, 2048, 2048, 2048, 512, 0, 8, 0,
         o_mu, 0, 256, 256, o_logvar, 256, 512, 256};
    gemm_kernel<<<dim3(8, 8), 256, 0, stream>>>(g, d_out, dflag);
    // MERGED: p1 = lrelu(z1 @ prior_w1^T)  ||  d1 = lrelu(concat(z1, h2) @ inf2_w1^T)
    ga = {inf1out, inf1out, nullptr, prior_w1, prior_b1, bufB,
          512, 256, 512, 256, 2048, 1, 32, 0,
          0, 0, 0, 0, 0, 0, 0, 0};
    gb = {inf1out, bufA, nullptr, inf2_w1, inf2_b1, bufD,
          512, 256, 2048, 2304, 2048, 1, 32, 0,
          0, 0, 0, 0, 0, 0, 0, 0};
    gemm2_kernel<<<dim3(64, 8), 256, 0, stream>>>(ga, gb, d_out, dflag);
    // MERGED: pfull = p1 @ prior_w2^T (+plogvar)  ||  dfull = d1 @ inf2_w2^T (+dmu,+dlogvar)
    ga = {bufB, bufB, nullptr, prior_w2, prior_b2, pfull,
          2048, 2048, 2048, 2048, 1536, 0, 24, 0,
          o_plogvar, 768, 1536, 768, 0, 0, 0, 0};
    gb = {bufD, bufD, nullptr, inf2_w2, inf2_b2, dfull,
          2048, 2048, 2048, 2048, 1536, 0, 24, 0,
          o_dmu, 0, 768, 768, o_dlogvar, 768, 1536, 768};
    gemm2_kernel<<<dim3(48, 8), 256, 0, stream>>>(ga, gb, d_out, dflag);
    // dech = lrelu((dfull[:, :768] + pfull[:, :768]) @ dec_w1^T)   (add fused via Aadd)
    g = {dfull, dfull, pfull, dec_w1, dec_b1, bufA,
         1536, 768, 1536, 768, 2048, 1, 32, 0,
         0, 0, 0, 0, 0, 0, 0, 0};
    gemm_kernel<<<dim3(32, 8), 256, 0, stream>>>(g, d_out, dflag);
    // cwr = dech @ dec_w2^T + fused cwrecon store
    g = {bufA, bufA, nullptr, dec_w2, dec_b2, cwr,
         2048, 2048, 2048, 2048, 4096, 0, 64, 0,
         o_cwrecon, 0, 4096, 4096, 0, 0, 0, 0};
    gemm_kernel<<<dim3(64, 8), 256, 0, stream>>>(g, d_out, dflag);

    // fused distances + argmin (writes o_cwdist and o_idx directly; fp64 kept here)
    dist_kernel<<<dim3(64, 16), 256, 0, stream>>>(cwr, codebook, bn,
                                                  d_out, o_cwdist, o_idx, dflag);
}

// Round 7
// 986.651 us; speedup vs baseline: 1.8125x; 1.0349x over previous
//
#include <hip/hip_runtime.h>
#include <hip/hip_bf16.h>

typedef __hip_bfloat16 bf16;
typedef unsigned short u16;

#define BATCH 512
#define CW_DIM 4096
#define DIM_CODES 64
#define BOOK_SIZE 1024
#define DIM_EMBED 64
#define ENC_H 512

// ---------------- dtype helpers (bf=1 -> bf16 inputs, bf=0 -> fp32) ----------------
__device__ __forceinline__ float bf2f(u16 u) {
    unsigned int x = ((unsigned int)u) << 16;
    return __uint_as_float(x);
}
__device__ __forceinline__ float loadf(const void* p, size_t i, int bf) {
    if (bf) return bf2f(((const u16*)p)[i]);
    return ((const float*)p)[i];
}
// vector load of 4 consecutive elements (i must be a multiple of 4)
__device__ __forceinline__ float4 load4(const void* p, size_t i, int bf) {
    if (bf) {
        const u16* q = (const u16*)p + i;
        uint2 raw = *reinterpret_cast<const uint2*>(q);
        float4 r;
        r.x = bf2f((u16)(raw.x & 0xFFFF));
        r.y = bf2f((u16)(raw.x >> 16));
        r.z = bf2f((u16)(raw.y & 0xFFFF));
        r.w = bf2f((u16)(raw.y >> 16));
        return r;
    }
    return *reinterpret_cast<const float4*>((const float*)p + i);
}
__device__ __forceinline__ void stored(void* p, size_t i, int bf, double v) {
    if (bf) ((bf16*)p)[i] = __float2bfloat16((float)v);
    else    ((float*)p)[i] = (float)v;
}
__device__ __forceinline__ u16 f2bfu(float v) {
    bf16 b = __float2bfloat16(v);
    return *reinterpret_cast<u16*>(&b);
}

// ---------------- dtype detector ----------------
__global__ void detect_kernel(const u16* __restrict__ x, int* __restrict__ flag) {
    __shared__ int hits;
    if (threadIdx.x == 0) hits = 0;
    __syncthreads();
    int h = 0;
    for (int i = threadIdx.x; i < 16384; i += 256) {
        u16 v = x[2 * i];
        if (((v >> 7) & 0xFF) == 0xFF) h++;
    }
    atomicAdd(&hits, h);
    __syncthreads();
    if (threadIdx.x == 0) *flag = (hits == 0) ? 1 : 0;  // 1 = bf16, 0 = fp32
}

// ---------------- codebook row norms (fp64, vectorized loads) ----------------
__global__ void booknorm_kernel(const void* __restrict__ book, double* __restrict__ bn,
                                const int* __restrict__ dflag) {
    const int bf = *dflag;
    int r = blockIdx.x * blockDim.x + threadIdx.x;
    if (r >= DIM_CODES * BOOK_SIZE) return;
    double acc = 0.0;
    for (int e = 0; e < DIM_EMBED; e += 4) {
        float4 v = load4(book, (size_t)r * DIM_EMBED + e, bf);
        acc = fma((double)v.x, (double)v.x, acc);
        acc = fma((double)v.y, (double)v.y, acc);
        acc = fma((double)v.z, (double)v.z, acc);
        acc = fma((double)v.w, (double)v.w, acc);
    }
    bn[r] = acc;
}

// ---------------- encoder conv + maxpool: 64c x 64h register-tiled mini-GEMM ----------------
__global__ __launch_bounds__(256) void enc_kernel(const void* __restrict__ x,
                                                  const void* __restrict__ w1,
                                                  const void* __restrict__ b1,
                                                  float* __restrict__ hmax,
                                                  const int* __restrict__ dflag) {
    const int bf = *dflag;
    __shared__ float xs_t[64][68];   // [e][c]
    __shared__ float wsh_t[64][68];  // [e][h]
    __shared__ float red[64][17];
    int t = threadIdx.x;
    int h0 = blockIdx.x * 64;
    int b = blockIdx.y;

    int cr = t >> 2;             // 0..63 (c row for x, h row for w1)
    int e0 = (t & 3) << 4;       // 0,16,32,48
    for (int q = 0; q < 4; q++) {
        int e = e0 + (q << 2);
        float4 xv = load4(x, (size_t)b * CW_DIM + cr * DIM_EMBED + e, bf);
        xs_t[e + 0][cr] = xv.x; xs_t[e + 1][cr] = xv.y;
        xs_t[e + 2][cr] = xv.z; xs_t[e + 3][cr] = xv.w;
        float4 wv = load4(w1, (size_t)(h0 + cr) * DIM_EMBED + e, bf);
        wsh_t[e + 0][cr] = wv.x; wsh_t[e + 1][cr] = wv.y;
        wsh_t[e + 2][cr] = wv.z; wsh_t[e + 3][cr] = wv.w;
    }
    __syncthreads();

    int th = t & 15, tc = t >> 4;   // thread tile: 4 c x 4 h
    float acc[4][4] = {};
    for (int e = 0; e < 64; e++) {
        float4 a4 = *(const float4*)&xs_t[e][tc << 2];
        float4 w4 = *(const float4*)&wsh_t[e][th << 2];
        float aa[4] = {a4.x, a4.y, a4.z, a4.w};
        float ww[4] = {w4.x, w4.y, w4.z, w4.w};
#pragma unroll
        for (int i = 0; i < 4; i++)
#pragma unroll
            for (int j = 0; j < 4; j++)
                acc[i][j] = fmaf(aa[i], ww[j], acc[i][j]);
    }
#pragma unroll
    for (int j = 0; j < 4; j++) {
        float bj = loadf(b1, h0 + (th << 2) + j, bf);
        float m = -1e30f;
#pragma unroll
        for (int i = 0; i < 4; i++) {
            float v = acc[i][j] + bj;
            v = v > 0.f ? v : 0.2f * v;
            m = fmaxf(m, v);
        }
        red[(th << 2) + j][tc] = m;
    }
    __syncthreads();
    if (t < 64) {
        float m = red[t][0];
        for (int k = 1; k < 16; k++) m = fmaxf(m, red[t][k]);
        hmax[(size_t)b * ENC_H + h0 + t] = m;
    }
}

// ---------------- GEMM descriptor + body (64x64 tile, 4x4/thread, dbuf + reg prefetch) ----------
struct GDesc {
    const float* A1; const float* A2; const float* Aadd;
    const void* W; const void* bias; float* C;
    int lda1, K1, lda2, Ktot, N, act, nbx, pad;
    size_t s0base; int s0c0, s0c1, s0stride;
    size_t s1base; int s1c0, s1c1, s1stride;
};

__device__ __forceinline__ void gemm_body(const GDesc& g, int bx, int by,
                                          void* __restrict__ out, const int bf) {
    __shared__ float As[2][16][68];
    __shared__ float Ws[2][16][68];
    int t = threadIdx.x;
    int tx = t & 15, ty = t >> 4;
    int n0 = bx * 64, m0 = by * 64;
    int mrow = t >> 2, kq = (t & 3) << 2;  // each thread stages one float4 of A and one of W
    float acc[4][4] = {};

    // ---- prefetch K-tile 0 ----
    float4 av, wv;
    {
        int k = kq;
        if (k < g.K1) {
            av = *reinterpret_cast<const float4*>(g.A1 + (size_t)(m0 + mrow) * g.lda1 + k);
            if (g.Aadd) {
                float4 ad = *reinterpret_cast<const float4*>(g.Aadd + (size_t)(m0 + mrow) * g.lda1 + k);
                av.x += ad.x; av.y += ad.y; av.z += ad.z; av.w += ad.w;
            }
        } else {
            av = *reinterpret_cast<const float4*>(g.A2 + (size_t)(m0 + mrow) * g.lda2 + (k - g.K1));
        }
        wv = load4(g.W, (size_t)(n0 + mrow) * g.Ktot + k, bf);
    }
    As[0][kq + 0][mrow] = av.x; As[0][kq + 1][mrow] = av.y;
    As[0][kq + 2][mrow] = av.z; As[0][kq + 3][mrow] = av.w;
    Ws[0][kq + 0][mrow] = wv.x; Ws[0][kq + 1][mrow] = wv.y;
    Ws[0][kq + 2][mrow] = wv.z; Ws[0][kq + 3][mrow] = wv.w;
    __syncthreads();

    int buf = 0;
#pragma unroll 1
    for (int kt = 0; kt < g.Ktot; kt += 16) {
        int nxt = kt + 16;
        if (nxt < g.Ktot) {  // issue next tile's global loads early
            int k = nxt + kq;
            if (k < g.K1) {
                av = *reinterpret_cast<const float4*>(g.A1 + (size_t)(m0 + mrow) * g.lda1 + k);
                if (g.Aadd) {
                    float4 ad = *reinterpret_cast<const float4*>(g.Aadd + (size_t)(m0 + mrow) * g.lda1 + k);
                    av.x += ad.x; av.y += ad.y; av.z += ad.z; av.w += ad.w;
                }
            } else {
                av = *reinterpret_cast<const float4*>(g.A2 + (size_t)(m0 + mrow) * g.lda2 + (k - g.K1));
            }
            wv = load4(g.W, (size_t)(n0 + mrow) * g.Ktot + k, bf);
        }
#pragma unroll
        for (int kk = 0; kk < 16; kk++) {
            float4 a4 = *(const float4*)&As[buf][kk][ty << 2];
            float4 w4 = *(const float4*)&Ws[buf][kk][tx << 2];
            float a[4] = {a4.x, a4.y, a4.z, a4.w};
            float w[4] = {w4.x, w4.y, w4.z, w4.w};
#pragma unroll
            for (int i = 0; i < 4; i++)
#pragma unroll
                for (int j = 0; j < 4; j++)
                    acc[i][j] = fmaf(a[i], w[j], acc[i][j]);
        }
        if (nxt < g.Ktot) {
            int nb = buf ^ 1;
            As[nb][kq + 0][mrow] = av.x; As[nb][kq + 1][mrow] = av.y;
            As[nb][kq + 2][mrow] = av.z; As[nb][kq + 3][mrow] = av.w;
            Ws[nb][kq + 0][mrow] = wv.x; Ws[nb][kq + 1][mrow] = wv.y;
            Ws[nb][kq + 2][mrow] = wv.z; Ws[nb][kq + 3][mrow] = wv.w;
            __syncthreads();
            buf = nb;
        }
    }

    int nbase = n0 + tx * 4;
    float b0 = loadf(g.bias, nbase + 0, bf), b1v = loadf(g.bias, nbase + 1, bf);
    float b2 = loadf(g.bias, nbase + 2, bf), b3 = loadf(g.bias, nbase + 3, bf);
#pragma unroll
    for (int i = 0; i < 4; i++) {
        int m = m0 + ty * 4 + i;
        float ov[4];
        ov[0] = acc[i][0] + b0; ov[1] = acc[i][1] + b1v;
        ov[2] = acc[i][2] + b2; ov[3] = acc[i][3] + b3;
        if (g.act) {
#pragma unroll
            for (int j = 0; j < 4; j++) ov[j] = ov[j] > 0.f ? ov[j] : 0.2f * ov[j];
        }
        float4 o = {ov[0], ov[1], ov[2], ov[3]};
        *reinterpret_cast<float4*>(g.C + (size_t)m * g.N + nbase) = o;
        if (nbase >= g.s0c0 && nbase < g.s0c1) {
            size_t off = g.s0base + (size_t)m * g.s0stride + (nbase - g.s0c0);
            if (bf) {
                ushort4 h = {f2bfu(ov[0]), f2bfu(ov[1]), f2bfu(ov[2]), f2bfu(ov[3])};
                *reinterpret_cast<ushort4*>((u16*)out + off) = h;
            } else {
                *reinterpret_cast<float4*>((float*)out + off) = o;
            }
        }
        if (nbase >= g.s1c0 && nbase < g.s1c1) {
            size_t off = g.s1base + (size_t)m * g.s1stride + (nbase - g.s1c0);
            if (bf) {
                ushort4 h = {f2bfu(ov[0]), f2bfu(ov[1]), f2bfu(ov[2]), f2bfu(ov[3])};
                *reinterpret_cast<ushort4*>((u16*)out + off) = h;
            } else {
                *reinterpret_cast<float4*>((float*)out + off) = o;
            }
        }
    }
}

__global__ __launch_bounds__(256) void gemm_kernel(GDesc g, void* __restrict__ out,
                                                   const int* __restrict__ dflag) {
    gemm_body(g, blockIdx.x, blockIdx.y, out, *dflag);
}

// two independent GEMMs in one dispatch; block-uniform descriptor select
__global__ __launch_bounds__(256) void gemm2_kernel(GDesc g0, GDesc g1, void* __restrict__ out,
                                                    const int* __restrict__ dflag) {
    const int bf = *dflag;
    bool first = (int)blockIdx.x < g0.nbx;
    GDesc g = first ? g0 : g1;
    int bx = first ? blockIdx.x : blockIdx.x - g0.nbx;
    gemm_body(g, bx, blockIdx.y, out, bf);
}

// ---------------- fused cw_dist (fp64) + exact argmin, transposed-LDS per-lane reads --------
// grid (c=64, btile=16) = 1024 blocks = 4/CU; block 256 = 4 waves; 32 b x 1024 s per block.
// LDS: xst[e][b] fp64 + bst[e][s] fp32 (both transposed) -> per-lane ds_read_b128 for BOTH
// operands (no broadcast waste). Thread (tx=t&15, ty=t>>4) owns 4 s-cols x 2 b-rows.
// Per e: 1 double2 + 1 float4 feed 8 fp64 FMA -> VALU-bound. 35 KB LDS -> 4 blocks/CU.
// fp64 FMA order per (b,s) is e-ascending (identical to prior rounds) -> bit-identical output.
__global__ __launch_bounds__(256, 4) void dist_kernel(const float* __restrict__ cwr,
                                                      const void* __restrict__ book,
                                                      const double* __restrict__ bn,
                                                      void* __restrict__ out,
                                                      size_t odist, size_t oidx,
                                                      const int* __restrict__ dflag) {
    const int bf = *dflag;
    __shared__ double xst[64][34];   // [e][b] transposed cwr slice, 17.4 KB
    __shared__ float  bst[64][68];   // [e][s] transposed book tile, 17.4 KB
    __shared__ double xn[32];
    int t = threadIdx.x;
    int c = blockIdx.x;
    int b0 = blockIdx.y * 32;
    int tx = t & 15, ty = t >> 4;    // tx -> 4 s-cols, ty -> 2 b-rows

    // ---- stage xst (transposed): thread covers b-pair (t>>4)*2, e-quad (t&15)*4
    {
        int bp = (t >> 4) << 1, e4 = (t & 15) << 2;
        float4 xa = *reinterpret_cast<const float4*>(cwr + (size_t)(b0 + bp) * CW_DIM + c * DIM_EMBED + e4);
        float4 xb = *reinterpret_cast<const float4*>(cwr + (size_t)(b0 + bp + 1) * CW_DIM + c * DIM_EMBED + e4);
        double2 w;
        w.x = (double)xa.x; w.y = (double)xb.x; *(double2*)&xst[e4 + 0][bp] = w;
        w.x = (double)xa.y; w.y = (double)xb.y; *(double2*)&xst[e4 + 1][bp] = w;
        w.x = (double)xa.z; w.y = (double)xb.z; *(double2*)&xst[e4 + 2][bp] = w;
        w.x = (double)xa.w; w.y = (double)xb.w; *(double2*)&xst[e4 + 3][bp] = w;
    }
    // ---- stage bst tile 0 (transposed): thread covers s-pair (t>>3)*2, e-oct (t&7)*8
    {
        int sp = (t >> 3) << 1, e8 = (t & 7) << 3;
        size_t base = ((size_t)c * BOOK_SIZE + sp) * DIM_EMBED + e8;
        float4 p0 = load4(book, base, bf);
        float4 p1 = load4(book, base + 4, bf);
        float4 p2 = load4(book, base + DIM_EMBED, bf);
        float4 p3 = load4(book, base + DIM_EMBED + 4, bf);
        float2 f;
        f.x = p0.x; f.y = p2.x; *(float2*)&bst[e8 + 0][sp] = f;
        f.x = p0.y; f.y = p2.y; *(float2*)&bst[e8 + 1][sp] = f;
        f.x = p0.z; f.y = p2.z; *(float2*)&bst[e8 + 2][sp] = f;
        f.x = p0.w; f.y = p2.w; *(float2*)&bst[e8 + 3][sp] = f;
        f.x = p1.x; f.y = p3.x; *(float2*)&bst[e8 + 4][sp] = f;
        f.x = p1.y; f.y = p3.y; *(float2*)&bst[e8 + 5][sp] = f;
        f.x = p1.z; f.y = p3.z; *(float2*)&bst[e8 + 6][sp] = f;
        f.x = p1.w; f.y = p3.w; *(float2*)&bst[e8 + 7][sp] = f;
    }
    __syncthreads();
    if (t < 32) {  // xn: same fma(v,v) e-ascending order as prior rounds
        double a = 0.0;
        for (int e = 0; e < 64; e++) { double v = xst[e][t]; a = fma(v, v, a); }
        xn[t] = a;
    }
    __syncthreads();

    double xnb0 = xn[ty << 1], xnb1 = xn[(ty << 1) + 1];  // wave-uniform per 16-lane group

    double bd[2];
    int bsx[2];
    bd[0] = 1e300; bd[1] = 1e300; bsx[0] = 0; bsx[1] = 0;

#pragma unroll 1
    for (int st = 0; st < 16; st++) {
        int s0 = st * 64;
        // early-issue: next tile's book loads into registers (hidden under compute)
        float4 pf0, pf1, pf2, pf3;
        int sp = (t >> 3) << 1, e8 = (t & 7) << 3;
        if (st < 15) {
            size_t base = ((size_t)c * BOOK_SIZE + s0 + 64 + sp) * DIM_EMBED + e8;
            pf0 = load4(book, base, bf);
            pf1 = load4(book, base + 4, bf);
            pf2 = load4(book, base + DIM_EMBED, bf);
            pf3 = load4(book, base + DIM_EMBED + 4, bf);
        }
        // early-issue: bn for this tile's 4 s-cols (consumed after the e-loop)
        const double* bnp = bn + ((size_t)c << 10) + s0 + (tx << 2);
        double2 bn01 = *reinterpret_cast<const double2*>(bnp);
        double2 bn23 = *reinterpret_cast<const double2*>(bnp + 2);

        double acc[2][4] = {};
#pragma unroll 8
        for (int e = 0; e < 64; e++) {
            double2 xv = *(const double2*)&xst[e][ty << 1];
            float4 bv = *(const float4*)&bst[e][tx << 2];
            double bv0 = (double)bv.x, bv1 = (double)bv.y;
            double bv2 = (double)bv.z, bv3 = (double)bv.w;
            acc[0][0] = fma(xv.x, bv0, acc[0][0]);
            acc[0][1] = fma(xv.x, bv1, acc[0][1]);
            acc[0][2] = fma(xv.x, bv2, acc[0][2]);
            acc[0][3] = fma(xv.x, bv3, acc[0][3]);
            acc[1][0] = fma(xv.y, bv0, acc[1][0]);
            acc[1][1] = fma(xv.y, bv1, acc[1][1]);
            acc[1][2] = fma(xv.y, bv2, acc[1][2]);
            acc[1][3] = fma(xv.y, bv3, acc[1][3]);
        }
        int sbase = s0 + (tx << 2);
#pragma unroll
        for (int ib = 0; ib < 2; ib++) {
            int b = (ty << 1) + ib;
            double xnb = ib ? xnb1 : xnb0;
            double d0 = xnb + bn01.x - 2.0 * acc[ib][0];
            double d1 = xnb + bn01.y - 2.0 * acc[ib][1];
            double d2 = xnb + bn23.x - 2.0 * acc[ib][2];
            double d3 = xnb + bn23.y - 2.0 * acc[ib][3];
            if (d0 < bd[ib]) { bd[ib] = d0; bsx[ib] = sbase + 0; }
            if (d1 < bd[ib]) { bd[ib] = d1; bsx[ib] = sbase + 1; }
            if (d2 < bd[ib]) { bd[ib] = d2; bsx[ib] = sbase + 2; }
            if (d3 < bd[ib]) { bd[ib] = d3; bsx[ib] = sbase + 3; }
            size_t off = odist + ((size_t)(b0 + b) * DIM_CODES + c) * BOOK_SIZE + sbase;
            if (bf) {
                ushort4 h = {f2bfu((float)d0), f2bfu((float)d1), f2bfu((float)d2), f2bfu((float)d3)};
                *reinterpret_cast<ushort4*>((u16*)out + off) = h;
            } else {
                float4 o = {(float)d0, (float)d1, (float)d2, (float)d3};
                *reinterpret_cast<float4*>((float*)out + off) = o;
            }
        }
        if (st < 15) {
            __syncthreads();   // all readers done with bst
            float2 f;
            f.x = pf0.x; f.y = pf2.x; *(float2*)&bst[e8 + 0][sp] = f;
            f.x = pf0.y; f.y = pf2.y; *(float2*)&bst[e8 + 1][sp] = f;
            f.x = pf0.z; f.y = pf2.z; *(float2*)&bst[e8 + 2][sp] = f;
            f.x = pf0.w; f.y = pf2.w; *(float2*)&bst[e8 + 3][sp] = f;
            f.x = pf1.x; f.y = pf3.x; *(float2*)&bst[e8 + 4][sp] = f;
            f.x = pf1.y; f.y = pf3.y; *(float2*)&bst[e8 + 5][sp] = f;
            f.x = pf1.z; f.y = pf3.z; *(float2*)&bst[e8 + 6][sp] = f;
            f.x = pf1.w; f.y = pf3.w; *(float2*)&bst[e8 + 7][sp] = f;
            __syncthreads();   // next tile ready
        }
    }
    // ---- argmin reduce across the 16 tx lanes of each ty group (shfl_xor stays in-group)
#pragma unroll
    for (int ib = 0; ib < 2; ib++) {
        double d = bd[ib];
        int s = bsx[ib];
        for (int off = 8; off >= 1; off >>= 1) {
            double od = __shfl_xor(d, off, 64);
            int os = __shfl_xor(s, off, 64);
            if (od < d || (od == d && os < s)) { d = od; s = os; }
        }
        if (tx == 0)
            stored(out, oidx + (size_t)(b0 + (ty << 1) + ib) * DIM_CODES + c, bf, (double)s);
    }
}

extern "C" void kernel_launch(void* const* d_in, const int* in_sizes, int n_in,
                              void* d_out, int out_size, void* d_ws, size_t ws_size,
                              hipStream_t stream) {
    const void* x        = d_in[0];
    const void* codebook = d_in[1];
    const void* enc_w1   = d_in[2];
    const void* enc_b1   = d_in[3];
    const void* enc_w2   = d_in[4];
    const void* enc_b2   = d_in[5];
    const void* inf1_w   = d_in[6];
    const void* inf1_b   = d_in[7];
    const void* inf2_w1  = d_in[8];
    const void* inf2_b1  = d_in[9];
    const void* inf2_w2  = d_in[10];
    const void* inf2_b2  = d_in[11];
    const void* prior_w1 = d_in[12];
    const void* prior_b1 = d_in[13];
    const void* prior_w2 = d_in[14];
    const void* prior_b2 = d_in[15];
    const void* dec_w1   = d_in[16];
    const void* dec_b1   = d_in[17];
    const void* dec_w2   = d_in[18];
    const void* dec_b2   = d_in[19];

    // ---- fp32 workspace with aliasing (~30 MB) ----
    float* W0 = (float*)d_ws;
    float* inf1out = W0;                   // 512*512           [live to end]
    float* pfull   = inf1out + 262144;     // 512*1536          [live to end]
    float* dfull   = pfull + 786432;       // 512*1536          [live to end]
    float* cwr     = dfull + 786432;       // 512*4096          [live to end]
    float* bufA    = cwr + 2097152;        // 512*2048: h2, later dech
    float* bufB    = bufA + 1048576;       // 512*2048: p1
    float* bufD    = bufB + 1048576;       // 512*2048: d1 (separate: p1/d1 run concurrently)
    float* bufC    = bufD + 1048576;       // 512*512: hmax
    double* bn     = (double*)(bufC + 262144);  // 64*1024 doubles
    int* dflag     = (int*)(bn + 65536);

    // ---- output slice element offsets (return order) ----
    const size_t o_cwrecon = 0;
    const size_t o_cwdist  = 2097152;
    const size_t o_idx     = 35651584;
    const size_t o_mu      = 35684352;
    const size_t o_logvar  = 35815424;
    const size_t o_dmu     = 35946496;
    const size_t o_dlogvar = 36339712;
    const size_t o_plogvar = 36732928;

    detect_kernel<<<1, 256, 0, stream>>>((const u16*)x, dflag);
    booknorm_kernel<<<256, 256, 0, stream>>>(codebook, bn, dflag);
    enc_kernel<<<dim3(8, BATCH), 256, 0, stream>>>(x, enc_w1, enc_b1, bufC, dflag);  // hmax -> bufC

    GDesc g, ga, gb;
    // h2 = hmax @ enc_w2^T
    g = {bufC, bufC, nullptr, enc_w2, enc_b2, bufA,
         512, 512, 512, 512, 2048, 0, 32, 0,
         0, 0, 0, 0, 0, 0, 0, 0};
    gemm_kernel<<<dim3(32, 8), 256, 0, stream>>>(g, d_out, dflag);
    // inf1out = h2 @ inf1_w^T (mu | log_var) + fused mu/logvar stores
    g = {bufA, bufA, nullptr, inf1_w, inf1_b, inf1out,
         2048, 2048, 2048, 2048, 512, 0, 8, 0,
         o_mu, 0, 256, 256, o_logvar, 256, 512, 256};
    gemm_kernel<<<dim3(8, 8), 256, 0, stream>>>(g, d_out, dflag);
    // MERGED: p1 = lrelu(z1 @ prior_w1^T)  ||  d1 = lrelu(concat(z1, h2) @ inf2_w1^T)
    ga = {inf1out, inf1out, nullptr, prior_w1, prior_b1, bufB,
          512, 256, 512, 256, 2048, 1, 32, 0,
          0, 0, 0, 0, 0, 0, 0, 0};
    gb = {inf1out, bufA, nullptr, inf2_w1, inf2_b1, bufD,
          512, 256, 2048, 2304, 2048, 1, 32, 0,
          0, 0, 0, 0, 0, 0, 0, 0};
    gemm2_kernel<<<dim3(64, 8), 256, 0, stream>>>(ga, gb, d_out, dflag);
    // MERGED: pfull = p1 @ prior_w2^T (+plogvar)  ||  dfull = d1 @ inf2_w2^T (+dmu,+dlogvar)
    ga = {bufB, bufB, nullptr, prior_w2, prior_b2, pfull,
          2048, 2048, 2048, 2048, 1536, 0, 24, 0,
          o_plogvar, 768, 1536, 768, 0, 0, 0, 0};
    gb = {bufD, bufD, nullptr, inf2_w2, inf2_b2, dfull,
          2048, 2048, 2048, 2048, 1536, 0, 24, 0,
          o_dmu, 0, 768, 768, o_dlogvar, 768, 1536, 768};
    gemm2_kernel<<<dim3(48, 8), 256, 0, stream>>>(ga, gb, d_out, dflag);
    // dech = lrelu((dfull[:, :768] + pfull[:, :768]) @ dec_w1^T)   (add fused via Aadd)
    g = {dfull, dfull, pfull, dec_w1, dec_b1, bufA,
         1536, 768, 1536, 768, 2048, 1, 32, 0,
         0, 0, 0, 0, 0, 0, 0, 0};
    gemm_kernel<<<dim3(32, 8), 256, 0, stream>>>(g, d_out, dflag);
    // cwr = dech @ dec_w2^T + fused cwrecon store
    g = {bufA, bufA, nullptr, dec_w2, dec_b2, cwr,
         2048, 2048, 2048, 2048, 4096, 0, 64, 0,
         o_cwrecon, 0, 4096, 4096, 0, 0, 0, 0};
    gemm_kernel<<<dim3(64, 8), 256, 0, stream>>>(g, d_out, dflag);

    // fused distances + argmin (writes o_cwdist and o_idx directly; fp64 kept here)
    dist_kernel<<<dim3(64, 16), 256, 0, stream>>>(cwr, codebook, bn,
                                                  d_out, o_cwdist, o_idx, dflag);
}